// Round 5
// baseline (422.358 us; speedup 1.0000x reference)
//
#include <hip/hip_runtime.h>
#include <math.h>

#define HW (512 * 512)
#define NB 16
#define NTHR 256
#define GXS 64          // blocks per batch: 64 blocks * 256 thr * 16 px = HW
#define CH 4            // chunks per thread (4 px each) = 16 px/thread
#define PREP 4          // replicas for k_pix accumulator atomics
#define ACCW 56         // padded stride of the 53-value per-block partials

// ---- workspace layout (4-byte words) ----
// Only [OFF_NEGMX .. OFF_TICK2] needs zeroing each launch (1.2 KB memset).
#define OFF_ACC    0                            // f [NB][GXS][ACCW] per-block partials
#define OFF_NEGMX  (OFF_ACC + NB * GXS * ACCW)  // u [NB] per-batch max(~negkey)
#define OFF_PACC   (OFF_NEGMX + NB)             // f [PREP][NB][4]
#define OFF_TICKS  (OFF_PACC + PREP * NB * 4)   // u [NB] k_stats per-batch tickets
#define OFF_TICK2  (OFF_TICKS + NB)             // u [1]  k_pix grid ticket
#define ZERO_OFF   OFF_NEGMX
#define ZERO_WORDS (NB + PREP * NB * 4 + NB + 1)
#define OFF_KDICE  (OFF_TICK2 + 1)              // f [NB][3] ak,bk,ck
#define OFF_TBL    (OFF_KDICE + NB * 3)         // f [NB][9][5] rows0..8={a0..a3,w}
#define OFF_THR    (OFF_TBL + NB * 45)          // f [NB]
#define OFF_FB     (OFF_THR + NB)               // u [NB]
#define OFF_NVAL   (OFF_FB + NB)                // u [NB]
#define OFF_DISCR  (OFF_NVAL + NB)              // f [NB]

// partial value indices: 0-7 kcnt, 8-15 tcnt, 16-47 ksum, 48 pos,
//                        49 ak, 50 bk, 51 ck, 52 negcnt

__device__ __forceinline__ unsigned fmap(float f) {
    unsigned u = __float_as_uint(f);
    return (u & 0x80000000u) ? ~u : (u | 0x80000000u);
}
__device__ __forceinline__ float funmap(unsigned u) {
    return (u & 0x80000000u) ? __uint_as_float(u & 0x7FFFFFFFu)
                             : __uint_as_float(~u);
}
__device__ __forceinline__ float wred(float x) {
#pragma unroll
    for (int o = 32; o; o >>= 1) x += __shfl_xor(x, o);
    return x;
}
__device__ __forceinline__ unsigned wredumax(unsigned x) {
#pragma unroll
    for (int o = 32; o; o >>= 1) x = max(x, (unsigned)__shfl_xor((int)x, o));
    return x;
}
__device__ __forceinline__ float agent_loadf(const float* p) {
    return __hip_atomic_load(p, __ATOMIC_RELAXED, __HIP_MEMORY_SCOPE_AGENT);
}

// ---------------- K1: stats + kernel-dice + fused per-batch setup ----------------
// Inner loop byte-identical to the round-0 baseline (48-VGPR local optimum;
// rounds 2-4 proved re-scheduling it regresses). Removed: key compaction
// (dead weight — fast path always taken; radix kept as raw-scan fallback in the
// fused sel). Added: per-batch ticket so the last block of each batch runs the
// former k_sel inline (threadfence + agent-scope atomic loads of partials).
__global__ __launch_bounds__(NTHR, 2) void k_stats(const float* __restrict__ preds,
                        const int* __restrict__ text,
                        const int* __restrict__ kern,
                        const int* __restrict__ mask,
                        unsigned* __restrict__ wsu) {
    float* wsf = (float*)wsu;
    const int b = blockIdx.y;
    const int tid = threadIdx.x;
    const int lane = tid & 63;
    __shared__ float sacc[53];
    __shared__ unsigned smx;
    __shared__ unsigned s_last;
    __shared__ float s_sum[53];
    __shared__ float s_avg[8][4];
    __shared__ int s_valid[8];
    __shared__ unsigned s_hist[256];
    __shared__ unsigned s_kk, s_prefix;
    if (tid < 53) sacc[tid] = 0.f;
    if (tid == 0) smx = 0u;
    __syncthreads();

    const int* tb = text + b * HW;
    const int* kb = kern + b * HW;
    const int* mb = mask + b * HW;
    const float* p0 = preds + (size_t)(b * 6 + 0) * HW;
    const float* p1 = preds + (size_t)(b * 6 + 1) * HW;
    const float* e0 = preds + (size_t)(b * 6 + 2) * HW;
    const float* e1 = e0 + HW;
    const float* e2 = e0 + 2 * HW;
    const float* e3 = e0 + 3 * HW;

    unsigned negc = 0u;
    unsigned mkAll = 0u;

    float ks[32];
#pragma unroll
    for (int i = 0; i < 32; i++) ks[i] = 0.f;
    float r_ak = 0.f, r_bk = 0.f, r_ck = 0.f;
    unsigned kcW[8] = {0, 0, 0, 0, 0, 0, 0, 0};
    unsigned tcW[8] = {0, 0, 0, 0, 0, 0, 0, 0};
    unsigned posW = 0;

#pragma unroll 1
    for (int c = 0; c < CH; c++) {
        const int base = blockIdx.x * (NTHR * 4 * CH) + c * (NTHR * 4) + tid * 4;
        const int4 t4 = *(const int4*)(tb + base);
        const int4 k4 = *(const int4*)(kb + base);
        const int4 m4 = *(const int4*)(mb + base);
        const float4 s4 = *(const float4*)(p0 + base);
        const float4 q4 = *(const float4*)(p1 + base);
        const float4 a4 = *(const float4*)(e0 + base);
        const float4 b4 = *(const float4*)(e1 + base);
        const float4 c4 = *(const float4*)(e2 + base);
        const float4 d4 = *(const float4*)(e3 + base);

#define PIX(T, K, M, Q, A, B, C, D) do {                                     \
        bool pos_ = (T) > 0, mp_ = (M) > 0;                                  \
        float sm_ = (pos_ && mp_) ? 1.f : 0.f;                               \
        float sg_ = 1.f / (1.f + expf(-(Q)));                                \
        float ik_ = ((K) > 0) ? 1.f : 0.f;                                   \
        r_ak += sm_ * sg_ * ik_;                                             \
        r_bk += sm_ * sg_ * sg_;                                             \
        r_ck += sm_ * ik_;                                                   \
        posW += (unsigned)__popcll(__ballot(pos_ && mp_));                   \
        _Pragma("unroll")                                                    \
        for (int i_ = 0; i_ < 8; i_++) {                                     \
            bool hit_ = ((K) == i_ + 1);                                     \
            kcW[i_] += (unsigned)__popcll(__ballot(hit_));                   \
            tcW[i_] += (unsigned)__popcll(__ballot((T) == i_ + 1));          \
            float h_ = hit_ ? 1.f : 0.f;                                     \
            ks[i_ * 4 + 0] += h_ * (A);                                      \
            ks[i_ * 4 + 1] += h_ * (B);                                      \
            ks[i_ * 4 + 2] += h_ * (C);                                      \
            ks[i_ * 4 + 3] += h_ * (D);                                      \
        }                                                                    \
    } while (0)

        PIX(t4.x, k4.x, m4.x, q4.x, a4.x, b4.x, c4.x, d4.x);
        PIX(t4.y, k4.y, m4.y, q4.y, a4.y, b4.y, c4.y, d4.y);
        PIX(t4.z, k4.z, m4.z, q4.z, a4.z, b4.z, c4.z, d4.z);
        PIX(t4.w, k4.w, m4.w, q4.w, a4.w, b4.w, c4.w, d4.w);
#undef PIX

        // ---- negative count + min negative score (no key stores) ----
        negc += (unsigned)__popcll(__ballot(t4.x == 0));
        negc += (unsigned)__popcll(__ballot(t4.y == 0));
        negc += (unsigned)__popcll(__ballot(t4.z == 0));
        negc += (unsigned)__popcll(__ballot(t4.w == 0));
        unsigned mk = 0u;
        if (t4.x == 0) mk = max(mk, ~fmap(s4.x));
        if (t4.y == 0) mk = max(mk, ~fmap(s4.y));
        if (t4.z == 0) mk = max(mk, ~fmap(s4.z));
        if (t4.w == 0) mk = max(mk, ~fmap(s4.w));
        mkAll = max(mkAll, mk);
    }

    mkAll = wredumax(mkAll);
    if (lane == 0) atomicMax(&smx, mkAll);

    // ---- epilogue: wave butterfly -> LDS -> one plain per-block store ----
#pragma unroll
    for (int i = 0; i < 32; i++) {
        float v = wred(ks[i]);
        if (lane == 0) atomicAdd(&sacc[16 + i], v);
    }
    {
        float v = wred(r_ak); if (lane == 0) atomicAdd(&sacc[49], v);
        v = wred(r_bk); if (lane == 0) atomicAdd(&sacc[50], v);
        v = wred(r_ck); if (lane == 0) atomicAdd(&sacc[51], v);
    }
    if (lane == 0) {
#pragma unroll
        for (int i = 0; i < 8; i++) {
            atomicAdd(&sacc[i], (float)kcW[i]);
            atomicAdd(&sacc[8 + i], (float)tcW[i]);
        }
        atomicAdd(&sacc[48], (float)posW);
        atomicAdd(&sacc[52], (float)negc);
    }
    __syncthreads();
    if (tid < 53)
        wsf[OFF_ACC + (b * GXS + blockIdx.x) * ACCW + tid] = sacc[tid];
    if (tid == 0 && smx) atomicMax(&wsu[OFF_NEGMX + b], smx);
    __threadfence();
    __syncthreads();
    if (tid == 0) {
        unsigned t = atomicAdd(&wsu[OFF_TICKS + b], 1u);
        s_last = (t == (unsigned)(GXS - 1)) ? 1u : 0u;
    }
    __syncthreads();
    if (!s_last) return;

    // ================= fused per-batch setup (former k_sel) =================
    __threadfence();   // acquire: invalidate before reading other blocks' partials
    if (tid < 53) {
        float v = 0.f;
        const float* p = wsf + OFF_ACC + (size_t)b * GXS * ACCW + tid;
#pragma unroll 8
        for (int r = 0; r < GXS; r++) v += agent_loadf(p + r * ACCW);
        s_sum[tid] = v;
    }
    __syncthreads();
    if (tid < 8) {
        float kcf = s_sum[tid];
        float tcf = s_sum[8 + tid];
        int valid = (kcf > 0.f && tcf > 0.f) ? 1 : 0;
        float inv = 1.f / fmaxf(kcf, 1.f);
        float w = valid ? 1.f / fmaxf(tcf, 1.f) : 0.f;
#pragma unroll
        for (int c = 0; c < 4; c++) {
            float a = s_sum[16 + tid * 4 + c] * inv;
            s_avg[tid][c] = a;
            wsf[OFF_TBL + b * 45 + (tid + 1) * 5 + c] = a;
        }
        s_valid[tid] = valid;
        wsf[OFF_TBL + b * 45 + (tid + 1) * 5 + 4] = w;
    }
    if (tid >= 8 && tid < 13) wsf[OFF_TBL + b * 45 + (tid - 8)] = 0.f;  // bg row
    if (tid >= 16 && tid < 19) wsf[OFF_KDICE + b * 3 + (tid - 16)] = s_sum[49 + (tid - 16)];
    if (tid < PREP * 4)  // zero this batch's k_pix accumulators
        wsf[OFF_PACC + ((tid >> 2) * NB + b) * 4 + (tid & 3)] = 0.f;
    __syncthreads();
    if (tid == 0) {
        int nval = 0;
        for (int i = 0; i < 8; i++) nval += s_valid[i];
        float L = 0.f;
        for (int i = 0; i < 8; i++)
            for (int j = i + 1; j < 8; j++)
                if (s_valid[i] && s_valid[j]) {
                    float sq = 0.f;
                    for (int c = 0; c < 4; c++) {
                        float d = s_avg[i][c] - s_avg[j][c];
                        sq += d * d;
                    }
                    float h = fmaxf(3.0f - sqrtf(sq), 0.f);
                    L += log1pf(h * h);
                }
        wsf[OFF_DISCR + b] = (nval > 1) ? L / fmaxf((float)(nval * (nval - 1)), 1.f) : 0.f;
        wsu[OFF_NVAL + b] = (unsigned)nval;
        unsigned pos = (unsigned)s_sum[48];
        unsigned neg = (unsigned)s_sum[52];
        unsigned nn = min(pos * 3u, neg);
        int fb = (pos == 0u || nn == 0u) ? 1 : 0;
        wsu[OFF_FB + b] = (unsigned)fb;
        wsf[OFF_THR + b] = 0.f;
        unsigned kk = fb ? 0u : nn;
        if (!fb && nn == neg) {
            // fast path: threshold = min negative score
            unsigned nm = (unsigned)__hip_atomic_load(&wsu[OFF_NEGMX + b],
                              __ATOMIC_RELAXED, __HIP_MEMORY_SCOPE_AGENT);
            wsf[OFF_THR + b] = funmap(~nm);
            kk = 0u;                        // skip radix
        }
        s_kk = kk;
        s_prefix = 0u;
    }
    __syncthreads();
    if (s_kk == 0u) return;                 // uniform exit: fb or fast path
    // -------- rare fallback: radix select over raw preds (1 block) --------
    unsigned prefix = 0u;
    for (int pass = 0; pass < 4; pass++) {
        const int shift = 24 - 8 * pass;
        const unsigned fmask = (pass == 0) ? 0u : (0xFFFFFFFFu << (shift + 8));
        s_hist[tid] = 0u;
        __syncthreads();
        for (int p = tid; p < HW; p += NTHR) {
            if (tb[p] == 0) {
                unsigned key = fmap(p0[p]);
                if ((key & fmask) == prefix) atomicAdd(&s_hist[(key >> shift) & 255u], 1u);
            }
        }
        __syncthreads();
        if (tid == 0) {
            unsigned k2 = s_kk;
            for (int bin = 255; bin >= 0; --bin) {
                unsigned c = s_hist[bin];
                if (k2 <= c) { s_prefix = prefix | (((unsigned)bin) << shift); s_kk = k2; break; }
                k2 -= c;
            }
        }
        __syncthreads();
        prefix = s_prefix;
    }
    if (tid == 0) wsf[OFF_THR + b] = funmap(prefix);
}

// ---------------- K2: fused aggregation + OHEM text-dice + final ----------------
__global__ __launch_bounds__(NTHR, 2) void k_pix(const float* __restrict__ preds,
                      const int* __restrict__ text,
                      const int* __restrict__ mask,
                      unsigned* __restrict__ wsu,
                      float* __restrict__ out) {
    float* wsf = (float*)wsu;
    const int b = blockIdx.y;
    const int tid = threadIdx.x;
    const int lane = tid & 63;
    __shared__ float stbl[45];
    __shared__ float sred[4];
    __shared__ float sthr;
    __shared__ unsigned sfb;
    __shared__ unsigned s_last;
    __shared__ float sfin[64];
    __shared__ float lt[NB], lk[NB], la[NB], ld[NB];
    if (tid < 45) stbl[tid] = wsf[OFF_TBL + b * 45 + tid];
    if (tid < 4) sred[tid] = 0.f;
    if (tid == 0) { sthr = wsf[OFF_THR + b]; sfb = wsu[OFF_FB + b]; }
    __syncthreads();
    const float thr = sthr;
    const bool fb = sfb != 0u;
    float r_at = 0.f, r_bt = 0.f, r_ct = 0.f, r_ag = 0.f;
    const int* tb = text + b * HW;
    const int* mb = mask + b * HW;
    const float* p0 = preds + (size_t)(b * 6) * HW;
    const float* e0 = preds + (size_t)(b * 6 + 2) * HW;
    const float* e1 = e0 + HW;
    const float* e2 = e0 + 2 * HW;
    const float* e3 = e0 + 3 * HW;

#pragma unroll 1
    for (int c = 0; c < CH; c++) {
        const int base = blockIdx.x * (NTHR * 4 * CH) + c * (NTHR * 4) + tid * 4;
        const int4 t4 = *(const int4*)(tb + base);
        const int4 m4 = *(const int4*)(mb + base);
        const float4 s4 = *(const float4*)(p0 + base);
        const float4 a4 = *(const float4*)(e0 + base);
        const float4 b4 = *(const float4*)(e1 + base);
        const float4 c4 = *(const float4*)(e2 + base);
        const float4 d4 = *(const float4*)(e3 + base);

#define PPIX(T, M, S, A, B, C, D) do {                                       \
        bool pos_ = (T) > 0;                                                 \
        bool samp_ = fb ? ((M) > 0) : ((((S) >= thr) || pos_) && ((M) > 0)); \
        float sg_ = 1.f / (1.f + expf(-(S)));                                \
        float smf_ = samp_ ? 1.f : 0.f;                                      \
        float it_ = pos_ ? 1.f : 0.f;                                        \
        r_at += smf_ * sg_ * it_;                                            \
        r_bt += smf_ * sg_ * sg_;                                            \
        r_ct += smf_ * it_;                                                  \
        int t5_ = min((T), 8) * 5;                                           \
        float d0_ = (A) - stbl[t5_ + 0];                                     \
        float d1_ = (B) - stbl[t5_ + 1];                                     \
        float d2_ = (C) - stbl[t5_ + 2];                                     \
        float d3_ = (D) - stbl[t5_ + 3];                                     \
        float w_ = stbl[t5_ + 4];                                            \
        float sq_ = d0_ * d0_ + d1_ * d1_ + d2_ * d2_ + d3_ * d3_;           \
        float dist_ = sqrtf(sq_ + 1e-12f) - 0.5f;                            \
        float hp_ = fmaxf(dist_, 0.f);                                       \
        r_ag += w_ * log1pf(hp_ * hp_);                                      \
    } while (0)

        PPIX(t4.x, m4.x, s4.x, a4.x, b4.x, c4.x, d4.x);
        PPIX(t4.y, m4.y, s4.y, a4.y, b4.y, c4.y, d4.y);
        PPIX(t4.z, m4.z, s4.z, a4.z, b4.z, c4.z, d4.z);
        PPIX(t4.w, m4.w, s4.w, a4.w, b4.w, c4.w, d4.w);
#undef PPIX
    }

    {
        float v = wred(r_at); if (lane == 0) atomicAdd(&sred[0], v);
        v = wred(r_bt); if (lane == 0) atomicAdd(&sred[1], v);
        v = wred(r_ct); if (lane == 0) atomicAdd(&sred[2], v);
        v = wred(r_ag); if (lane == 0) atomicAdd(&sred[3], v);
    }
    __syncthreads();
    if (tid < 4) {
        const int rep = blockIdx.x & (PREP - 1);
        atomicAdd(&wsf[OFF_PACC + (rep * NB + b) * 4 + tid], sred[tid]);
    }
    // ---- last-block-done: fold the final assembly in ----
    __threadfence();
    if (tid == 0) {
        unsigned t = atomicAdd(&wsu[OFF_TICK2], 1u);
        s_last = (t == (unsigned)(GXS * NB - 1)) ? 1u : 0u;
    }
    __syncthreads();
    if (!s_last) return;
    if (tid < 64) {
        const int bb = tid >> 2, v = tid & 3;
        float s = 0.f;
#pragma unroll
        for (int r = 0; r < PREP; r++)
            s += atomicAdd(&wsf[OFF_PACC + (r * NB + bb) * 4 + v], 0.f);  // coherent read
        sfin[tid] = s;
    }
    __syncthreads();
    if (tid < NB) {
        const float S = 1e-3f;
        float at = sfin[tid * 4 + 0], bt = sfin[tid * 4 + 1];
        float ct = sfin[tid * 4 + 2], ag = sfin[tid * 4 + 3];
        float ak = wsf[OFF_KDICE + tid * 3 + 0];
        float bk = wsf[OFF_KDICE + tid * 3 + 1];
        float ck = wsf[OFF_KDICE + tid * 3 + 2];
        lt[tid] = 1.f - 2.f * (at + S) / ((bt + S) + (ct + S));
        lk[tid] = 1.f - 2.f * (ak + S) / ((bk + S) + (ck + S));
        int nval = (int)wsu[OFF_NVAL + tid];
        la[tid] = (nval > 0) ? ag / fmaxf((float)nval, 1.f) : 0.f;
        ld[tid] = wsf[OFF_DISCR + tid];
    }
    __syncthreads();
    if (tid == 0) {
        float st = 0, sk = 0, sa = 0, sd = 0;
        for (int i = 0; i < NB; i++) { st += lt[i]; sk += lk[i]; sa += la[i]; sd += ld[i]; }
        out[0] = st / NB;
        out[1] = 0.5f * sk / NB;
        out[2] = 0.25f * sa / NB;
        out[3] = 0.25f * sd / NB;
    }
}

extern "C" void kernel_launch(void* const* d_in, const int* in_sizes, int n_in,
                              void* d_out, int out_size, void* d_ws, size_t ws_size,
                              hipStream_t stream) {
    const float* preds = (const float*)d_in[0];
    const int* text = (const int*)d_in[1];
    const int* kern = (const int*)d_in[2];
    const int* mask = (const int*)d_in[3];
    unsigned* wsu = (unsigned*)d_ws;
    float* out = (float*)d_out;

    // zero only tickets + negmax + PACC (1.2 KB) — robust to workspace poison
    (void)hipMemsetAsync((char*)d_ws + (size_t)ZERO_OFF * 4, 0,
                         (size_t)ZERO_WORDS * 4, stream);

    dim3 grid(GXS, NB);
    k_stats<<<grid, NTHR, 0, stream>>>(preds, text, kern, mask, wsu);
    k_pix<<<grid, NTHR, 0, stream>>>(preds, text, mask, wsu, out);
}

// Round 7
// 238.338 us; speedup vs baseline: 1.7721x; 1.7721x over previous
//
#include <hip/hip_runtime.h>
#include <math.h>

#define HW (512 * 512)
#define NB 16
#define NTHR 256
#define GXS 64          // blocks per batch: 64 blocks * 256 thr * 16 px = HW
#define CH 4            // chunks per thread (4 px each) = 16 px/thread
#define ACCW 56         // padded stride of the 53-value per-block partials

// ---- workspace layout (4-byte words). NOTHING is pre-zeroed: every word is
// written unconditionally before it is read (poison-robust). Coherence comes
// from kernel dispatch boundaries only — round-5 lesson: device-scope fences
// (threadfence/tickets) inside hot kernels cost ~2.5x via L2 writeback/inv. ----
#define OFF_ACC    0                            // f [NB][GXS][ACCW] k_stats partials
#define OFF_NEGMX  (OFF_ACC + NB * GXS * ACCW)  // u [NB][GXS] per-block max(~negkey)
#define OFF_PPART  (OFF_NEGMX + NB * GXS)       // f [NB][GXS][4] k_pix partials
#define OFF_KDICE  (OFF_PPART + NB * GXS * 4)   // f [NB][3] ak,bk,ck
#define OFF_NVAL   (OFF_KDICE + NB * 3)         // u [NB]
#define OFF_DISCR  (OFF_NVAL + NB)              // f [NB]

// partial value indices: 0-7 kcnt, 8-15 tcnt, 16-47 ksum, 48 pos,
//                        49 ak, 50 bk, 51 ck, 52 negcnt

__device__ __forceinline__ unsigned fmap(float f) {
    unsigned u = __float_as_uint(f);
    return (u & 0x80000000u) ? ~u : (u | 0x80000000u);
}
__device__ __forceinline__ float funmap(unsigned u) {
    return (u & 0x80000000u) ? __uint_as_float(u & 0x7FFFFFFFu)
                             : __uint_as_float(~u);
}
__device__ __forceinline__ float wred(float x) {
#pragma unroll
    for (int o = 32; o; o >>= 1) x += __shfl_xor(x, o);
    return x;
}
__device__ __forceinline__ unsigned wredumax(unsigned x) {
#pragma unroll
    for (int o = 32; o; o >>= 1) x = max(x, (unsigned)__shfl_xor((int)x, o));
    return x;
}
__device__ __forceinline__ unsigned long long wredull(unsigned long long x) {
#pragma unroll
    for (int o = 32; o; o >>= 1)
        x += (unsigned long long)__shfl_xor((unsigned long long)x, o);
    return x;
}

// ---------------- K1: stats + kernel-dice partials ----------------
// Round-0 inner loop (48-VGPR local optimum; rounds 2-4 proved re-scheduling it
// regresses) minus compaction (dead weight: fast path always taken) minus
// ballots (tcnt via packed u64, pos via float add, negcnt via PER-THREAD bool
// adds — round-6 bug: ballot-aggregated negc + butterfly double-counted x64).
__global__ __launch_bounds__(NTHR, 2) void k_stats(const float* __restrict__ preds,
                        const int* __restrict__ text,
                        const int* __restrict__ kern,
                        const int* __restrict__ mask,
                        unsigned* __restrict__ wsu) {
    float* wsf = (float*)wsu;
    const int b = blockIdx.y;
    const int tid = threadIdx.x;
    const int lane = tid & 63;
    __shared__ float sacc[53];
    __shared__ unsigned smx;
    if (tid < 53) sacc[tid] = 0.f;
    if (tid == 0) smx = 0u;
    __syncthreads();

    const int* tb = text + b * HW;
    const int* kb = kern + b * HW;
    const int* mb = mask + b * HW;
    const float* p0 = preds + (size_t)(b * 6 + 0) * HW;
    const float* p1 = preds + (size_t)(b * 6 + 1) * HW;
    const float* e0 = preds + (size_t)(b * 6 + 2) * HW;
    const float* e1 = e0 + HW;
    const float* e2 = e0 + 2 * HW;
    const float* e3 = e0 + 3 * HW;

    unsigned negc = 0u;   // per-thread count of text==0 pixels
    unsigned mkAll = 0u;

    float ks[32];
#pragma unroll
    for (int i = 0; i < 32; i++) ks[i] = 0.f;
    float r_ak = 0.f, r_bk = 0.f, r_ck = 0.f, r_pos = 0.f;
    unsigned kcW[8] = {0, 0, 0, 0, 0, 0, 0, 0};
    unsigned long long tpack = 0ull;  // 8x8-bit per-thread text-counts (<=16/field)

#pragma unroll 1
    for (int c = 0; c < CH; c++) {
        const int base = blockIdx.x * (NTHR * 4 * CH) + c * (NTHR * 4) + tid * 4;
        const int4 t4 = *(const int4*)(tb + base);
        const int4 k4 = *(const int4*)(kb + base);
        const int4 m4 = *(const int4*)(mb + base);
        const float4 s4 = *(const float4*)(p0 + base);
        const float4 q4 = *(const float4*)(p1 + base);
        const float4 a4 = *(const float4*)(e0 + base);
        const float4 b4 = *(const float4*)(e1 + base);
        const float4 c4 = *(const float4*)(e2 + base);
        const float4 d4 = *(const float4*)(e3 + base);

#define PIX(T, K, M, Q, A, B, C, D) do {                                     \
        bool pos_ = (T) > 0, mp_ = (M) > 0;                                  \
        float sm_ = (pos_ && mp_) ? 1.f : 0.f;                               \
        float sg_ = 1.f / (1.f + expf(-(Q)));                                \
        float ik_ = ((K) > 0) ? 1.f : 0.f;                                   \
        r_ak += sm_ * sg_ * ik_;                                             \
        r_bk += sm_ * sg_ * sg_;                                             \
        r_ck += sm_ * ik_;                                                   \
        r_pos += sm_;                                                        \
        tpack += pos_ ? (1ull << ((((unsigned)(T) - 1u) & 7u) * 8u)) : 0ull; \
        _Pragma("unroll")                                                    \
        for (int i_ = 0; i_ < 8; i_++) {                                     \
            bool hit_ = ((K) == i_ + 1);                                     \
            kcW[i_] += (unsigned)__popcll(__ballot(hit_));                   \
            float h_ = hit_ ? 1.f : 0.f;                                     \
            ks[i_ * 4 + 0] += h_ * (A);                                      \
            ks[i_ * 4 + 1] += h_ * (B);                                      \
            ks[i_ * 4 + 2] += h_ * (C);                                      \
            ks[i_ * 4 + 3] += h_ * (D);                                      \
        }                                                                    \
    } while (0)

        PIX(t4.x, k4.x, m4.x, q4.x, a4.x, b4.x, c4.x, d4.x);
        PIX(t4.y, k4.y, m4.y, q4.y, a4.y, b4.y, c4.y, d4.y);
        PIX(t4.z, k4.z, m4.z, q4.z, a4.z, b4.z, c4.z, d4.z);
        PIX(t4.w, k4.w, m4.w, q4.w, a4.w, b4.w, c4.w, d4.w);
#undef PIX

        // ---- per-thread negative count + min negative score (no ballots) ----
        negc += (unsigned)(t4.x == 0) + (unsigned)(t4.y == 0)
              + (unsigned)(t4.z == 0) + (unsigned)(t4.w == 0);
        unsigned mk = 0u;
        if (t4.x == 0) mk = max(mk, ~fmap(s4.x));
        if (t4.y == 0) mk = max(mk, ~fmap(s4.y));
        if (t4.z == 0) mk = max(mk, ~fmap(s4.z));
        if (t4.w == 0) mk = max(mk, ~fmap(s4.w));
        mkAll = max(mkAll, mk);
    }

    mkAll = wredumax(mkAll);
    if (lane == 0) atomicMax(&smx, mkAll);

    // ---- epilogue: wave butterfly -> LDS -> plain per-block store ----
#pragma unroll
    for (int i = 0; i < 32; i++) {
        float v = wred(ks[i]);
        if (lane == 0) atomicAdd(&sacc[16 + i], v);
    }
    {
        float v = wred(r_ak); if (lane == 0) atomicAdd(&sacc[49], v);
        v = wred(r_bk); if (lane == 0) atomicAdd(&sacc[50], v);
        v = wred(r_ck); if (lane == 0) atomicAdd(&sacc[51], v);
        v = wred(r_pos); if (lane == 0) atomicAdd(&sacc[48], v);
        unsigned nv = negc;   // per-thread counts -> butterfly is correct here
#pragma unroll
        for (int o = 32; o; o >>= 1) nv += (unsigned)__shfl_xor((int)nv, o);
        if (lane == 0) atomicAdd(&sacc[52], (float)nv);
    }
    {
        // unpack 8x8-bit -> 2x(4x16-bit) so the 64-lane sum can't overflow
        unsigned long long lo = tpack & 0x00FF00FF00FF00FFull;          // inst 1,3,5,7
        unsigned long long hi = (tpack >> 8) & 0x00FF00FF00FF00FFull;   // inst 2,4,6,8
        lo = wredull(lo);
        hi = wredull(hi);
        if (lane == 0) {
            atomicAdd(&sacc[8 + 0], (float)(unsigned)( lo        & 0xFFFFull));
            atomicAdd(&sacc[8 + 2], (float)(unsigned)((lo >> 16) & 0xFFFFull));
            atomicAdd(&sacc[8 + 4], (float)(unsigned)((lo >> 32) & 0xFFFFull));
            atomicAdd(&sacc[8 + 6], (float)(unsigned)((lo >> 48) & 0xFFFFull));
            atomicAdd(&sacc[8 + 1], (float)(unsigned)( hi        & 0xFFFFull));
            atomicAdd(&sacc[8 + 3], (float)(unsigned)((hi >> 16) & 0xFFFFull));
            atomicAdd(&sacc[8 + 5], (float)(unsigned)((hi >> 32) & 0xFFFFull));
            atomicAdd(&sacc[8 + 7], (float)(unsigned)((hi >> 48) & 0xFFFFull));
        }
    }
    if (lane == 0) {
#pragma unroll
        for (int i = 0; i < 8; i++) atomicAdd(&sacc[i], (float)kcW[i]);
    }
    __syncthreads();
    if (tid < 53)
        wsf[OFF_ACC + (b * GXS + blockIdx.x) * ACCW + tid] = sacc[tid];
    if (tid == 0)
        wsu[OFF_NEGMX + b * GXS + blockIdx.x] = smx;
}

// ---------------- K2: redundant per-batch setup + aggregation + OHEM dice ----
// Each block recomputes its batch's setup from k_stats partials (fence-free:
// the dispatch boundary guarantees visibility; the redundant work is ~13
// L2-resident loads/thread). bx==0 additionally writes KDICE/NVAL/DISCR.
__global__ __launch_bounds__(NTHR, 2) void k_pix(const float* __restrict__ preds,
                      const int* __restrict__ text,
                      const int* __restrict__ mask,
                      unsigned* __restrict__ wsu) {
    float* wsf = (float*)wsu;
    const int b = blockIdx.y;
    const int tid = threadIdx.x;
    const int lane = tid & 63;
    __shared__ float s_sum[53];
    __shared__ float stbl[45];
    __shared__ int s_valid[8];
    __shared__ unsigned s_negmax;
    __shared__ float s_thr;
    __shared__ int s_fb;
    __shared__ unsigned s_kk, s_prefix;
    __shared__ unsigned s_hist[256];
    __shared__ float sred[4];

    const int* tb = text + b * HW;
    const int* mb = mask + b * HW;
    const float* p0 = preds + (size_t)(b * 6) * HW;
    const float* e0 = preds + (size_t)(b * 6 + 2) * HW;
    const float* e1 = e0 + HW;
    const float* e2 = e0 + 2 * HW;
    const float* e3 = e0 + 3 * HW;

    // ---- preamble: recompute batch setup from partials ----
    if (tid < 53) {
        float v = 0.f;
        const float* p = wsf + OFF_ACC + (size_t)b * GXS * ACCW + tid;
        for (int r = 0; r < GXS; r++) v += p[r * ACCW];
        s_sum[tid] = v;
    }
    if (tid >= 64 && tid < 128) {
        unsigned m = wsu[OFF_NEGMX + b * GXS + (tid - 64)];
        m = wredumax(m);
        if (tid == 64) s_negmax = m;
    }
    if (tid < 4) sred[tid] = 0.f;
    __syncthreads();
    if (tid < 8) {
        float kcf = s_sum[tid];
        float tcf = s_sum[8 + tid];
        int valid = (kcf > 0.f && tcf > 0.f) ? 1 : 0;
        s_valid[tid] = valid;
        float inv = 1.f / fmaxf(kcf, 1.f);
        float w = valid ? 1.f / fmaxf(tcf, 1.f) : 0.f;
#pragma unroll
        for (int c = 0; c < 4; c++)
            stbl[(tid + 1) * 5 + c] = s_sum[16 + tid * 4 + c] * inv;
        stbl[(tid + 1) * 5 + 4] = w;
    }
    if (tid >= 8 && tid < 13) stbl[tid - 8] = 0.f;   // bg row
    __syncthreads();
    if (tid == 0) {
        unsigned pos = (unsigned)s_sum[48];
        unsigned neg = (unsigned)s_sum[52];
        unsigned nn = min(pos * 3u, neg);
        int fb = (pos == 0u || nn == 0u) ? 1 : 0;
        s_fb = fb;
        unsigned kk = fb ? 0u : nn;
        float thr = 0.f;
        if (!fb && nn == neg) {           // fast path: min negative score
            thr = funmap(~s_negmax);
            kk = 0u;
        }
        s_thr = thr;
        s_kk = kk;
        s_prefix = 0u;
    }
    // bx==0 block: housekeeping for k_final
    if (blockIdx.x == 0) {
        if (tid >= 16 && tid < 19)
            wsf[OFF_KDICE + b * 3 + (tid - 16)] = s_sum[49 + (tid - 16)];
        if (tid == 32) {
            int nval = 0;
            for (int i = 0; i < 8; i++) nval += s_valid[i];
            wsu[OFF_NVAL + b] = (unsigned)nval;
            float L = 0.f;
            for (int i = 0; i < 8; i++)
                for (int j = i + 1; j < 8; j++)
                    if (s_valid[i] && s_valid[j]) {
                        float sq = 0.f;
                        for (int c = 0; c < 4; c++) {
                            float d = stbl[(i + 1) * 5 + c] - stbl[(j + 1) * 5 + c];
                            sq += d * d;
                        }
                        float h = fmaxf(3.0f - sqrtf(sq), 0.f);
                        L += log1pf(h * h);
                    }
            wsf[OFF_DISCR + b] = (nval > 1) ? L / fmaxf((float)(nval * (nval - 1)), 1.f) : 0.f;
        }
    }
    __syncthreads();
    // rare fallback: per-block radix select over raw preds (correct, slow,
    // never taken on fast-path data)
    if (s_kk != 0u) {
        unsigned prefix = 0u;
        for (int pass = 0; pass < 4; pass++) {
            const int shift = 24 - 8 * pass;
            const unsigned fmask = (pass == 0) ? 0u : (0xFFFFFFFFu << (shift + 8));
            s_hist[tid] = 0u;
            __syncthreads();
            for (int p = tid; p < HW; p += NTHR) {
                if (tb[p] == 0) {
                    unsigned key = fmap(p0[p]);
                    if ((key & fmask) == prefix) atomicAdd(&s_hist[(key >> shift) & 255u], 1u);
                }
            }
            __syncthreads();
            if (tid == 0) {
                unsigned k2 = s_kk;
                for (int bin = 255; bin >= 0; --bin) {
                    unsigned c = s_hist[bin];
                    if (k2 <= c) { s_prefix = prefix | (((unsigned)bin) << shift); s_kk = k2; break; }
                    k2 -= c;
                }
            }
            __syncthreads();
            prefix = s_prefix;
        }
        if (tid == 0) s_thr = funmap(prefix);
        __syncthreads();
    }
    const float thr = s_thr;
    const bool fb = s_fb != 0;

    // ---- main loop: round-0 body ----
    float r_at = 0.f, r_bt = 0.f, r_ct = 0.f, r_ag = 0.f;
#pragma unroll 1
    for (int c = 0; c < CH; c++) {
        const int base = blockIdx.x * (NTHR * 4 * CH) + c * (NTHR * 4) + tid * 4;
        const int4 t4 = *(const int4*)(tb + base);
        const int4 m4 = *(const int4*)(mb + base);
        const float4 s4 = *(const float4*)(p0 + base);
        const float4 a4 = *(const float4*)(e0 + base);
        const float4 b4 = *(const float4*)(e1 + base);
        const float4 c4 = *(const float4*)(e2 + base);
        const float4 d4 = *(const float4*)(e3 + base);

#define PPIX(T, M, S, A, B, C, D) do {                                       \
        bool pos_ = (T) > 0;                                                 \
        bool samp_ = fb ? ((M) > 0) : ((((S) >= thr) || pos_) && ((M) > 0)); \
        float sg_ = 1.f / (1.f + expf(-(S)));                                \
        float smf_ = samp_ ? 1.f : 0.f;                                      \
        float it_ = pos_ ? 1.f : 0.f;                                        \
        r_at += smf_ * sg_ * it_;                                            \
        r_bt += smf_ * sg_ * sg_;                                            \
        r_ct += smf_ * it_;                                                  \
        int t5_ = min((T), 8) * 5;                                           \
        float d0_ = (A) - stbl[t5_ + 0];                                     \
        float d1_ = (B) - stbl[t5_ + 1];                                     \
        float d2_ = (C) - stbl[t5_ + 2];                                     \
        float d3_ = (D) - stbl[t5_ + 3];                                     \
        float w_ = stbl[t5_ + 4];                                            \
        float sq_ = d0_ * d0_ + d1_ * d1_ + d2_ * d2_ + d3_ * d3_;           \
        float dist_ = sqrtf(sq_ + 1e-12f) - 0.5f;                            \
        float hp_ = fmaxf(dist_, 0.f);                                       \
        r_ag += w_ * log1pf(hp_ * hp_);                                      \
    } while (0)

        PPIX(t4.x, m4.x, s4.x, a4.x, b4.x, c4.x, d4.x);
        PPIX(t4.y, m4.y, s4.y, a4.y, b4.y, c4.y, d4.y);
        PPIX(t4.z, m4.z, s4.z, a4.z, b4.z, c4.z, d4.z);
        PPIX(t4.w, m4.w, s4.w, a4.w, b4.w, c4.w, d4.w);
#undef PPIX
    }

    {
        float v = wred(r_at); if (lane == 0) atomicAdd(&sred[0], v);
        v = wred(r_bt); if (lane == 0) atomicAdd(&sred[1], v);
        v = wred(r_ct); if (lane == 0) atomicAdd(&sred[2], v);
        v = wred(r_ag); if (lane == 0) atomicAdd(&sred[3], v);
    }
    __syncthreads();
    if (tid < 4)
        wsf[OFF_PPART + (b * GXS + blockIdx.x) * 4 + tid] = sred[tid];
}

// ---------------- K3: final assembly ----------------
__global__ void k_final(unsigned* __restrict__ wsu, float* __restrict__ out) {
    float* wsf = (float*)wsu;
    __shared__ float sfin[64];
    __shared__ float lt[NB], lk[NB], la[NB], ld[NB];
    const int tid = threadIdx.x;   // 64 threads
    {
        const int bb = tid >> 2, v = tid & 3;
        float s = 0.f;
        const float* p = wsf + OFF_PPART + (size_t)bb * GXS * 4 + v;
        for (int r = 0; r < GXS; r++) s += p[r * 4];
        sfin[tid] = s;
    }
    __syncthreads();
    if (tid < NB) {
        const float S = 1e-3f;
        float at = sfin[tid * 4 + 0], bt = sfin[tid * 4 + 1];
        float ct = sfin[tid * 4 + 2], ag = sfin[tid * 4 + 3];
        float ak = wsf[OFF_KDICE + tid * 3 + 0];
        float bk = wsf[OFF_KDICE + tid * 3 + 1];
        float ck = wsf[OFF_KDICE + tid * 3 + 2];
        lt[tid] = 1.f - 2.f * (at + S) / ((bt + S) + (ct + S));
        lk[tid] = 1.f - 2.f * (ak + S) / ((bk + S) + (ck + S));
        int nval = (int)wsu[OFF_NVAL + tid];
        la[tid] = (nval > 0) ? ag / fmaxf((float)nval, 1.f) : 0.f;
        ld[tid] = wsf[OFF_DISCR + tid];
    }
    __syncthreads();
    if (tid == 0) {
        float st = 0, sk = 0, sa = 0, sd = 0;
        for (int i = 0; i < NB; i++) { st += lt[i]; sk += lk[i]; sa += la[i]; sd += ld[i]; }
        out[0] = st / NB;
        out[1] = 0.5f * sk / NB;
        out[2] = 0.25f * sa / NB;
        out[3] = 0.25f * sd / NB;
    }
}

extern "C" void kernel_launch(void* const* d_in, const int* in_sizes, int n_in,
                              void* d_out, int out_size, void* d_ws, size_t ws_size,
                              hipStream_t stream) {
    const float* preds = (const float*)d_in[0];
    const int* text = (const int*)d_in[1];
    const int* kern = (const int*)d_in[2];
    const int* mask = (const int*)d_in[3];
    unsigned* wsu = (unsigned*)d_ws;
    float* out = (float*)d_out;

    dim3 grid(GXS, NB);
    k_stats<<<grid, NTHR, 0, stream>>>(preds, text, kern, mask, wsu);
    k_pix<<<grid, NTHR, 0, stream>>>(preds, text, mask, wsu);
    k_final<<<1, 64, 0, stream>>>(wsu, out);
}